// Round 14
// baseline (201.703 us; speedup 1.0000x reference)
//
#include <hip/hip_runtime.h>
#include <hip/hip_cooperative_groups.h>
#include <math.h>

#define LOG2E 1.4426950408889634f

namespace cg = cooperative_groups;

typedef short short8 __attribute__((ext_vector_type(8)));
typedef float f32x4  __attribute__((ext_vector_type(4)));

__device__ inline unsigned short f2bf(float f) {   // f32 -> bf16 bits, RNE
    unsigned int u = __float_as_uint(f);
    return (unsigned short)((u + 0x7FFFu + ((u >> 16) & 1u)) >> 16);
}

__device__ inline unsigned int cvtpk_bf16(float lo, float hi) {
    unsigned int r;
    asm("v_cvt_pk_bf16_f32 %0, %1, %2" : "=v"(r) : "v"(lo), "v"(hi));
    return r;   // low16 = bf16(lo), high16 = bf16(hi)
}

// ONE cooperative dispatch, 3 phases separated by grid.sync():
//  A: pack train into the B-fragment image in ws (64B/pt: 4 distinct 16B
//     variants: dims0-7 | dims8-15 | dims0-6+n0@slot7 | dims8-14+n1@slot7,
//     n0+n1 = -(0.5*log2e)*||y||^2; padded pts get -1e30 -> exp2 = 0).
//     Each block packs nPad/grid points; A-fragments prepped concurrently.
//  B: block b=(g,s): rows g*64..+63, train quarter s. Wave w=(r,q): row-tile
//     r, 512-pt slice q. Inner per 16-pt tile: 1 global b128 (L2-resident
//     image) + 1 mfma_16x16x32_bf16 (invariant C = -testnorm via slot trick)
//     + 4 exp2 + 4 add. No LDS staging, no converts, no atomics.
//     Cross-wave row combine via 1KB LDS; partials[s][row] plain store.
//  C: first G blocks: out[row] = log(sum_s partials[s][row]) - Z.
__global__ __launch_bounds__(1024, 4) void kde_coop(
    const float* __restrict__ testX, const float* __restrict__ trainX,
    uint4* __restrict__ pk, float* __restrict__ partials,
    float* __restrict__ out, int nTest, int nTrain, int TQ, int G, float Z)
{
    cg::grid_group gridg = cg::this_grid();

    const int tid  = threadIdx.x;
    const int lane = tid & 63;
    const int w    = tid >> 6;            // wave 0..15
    const int g4   = lane >> 4;           // MFMA lane group 0..3
    const int l4   = lane & 15;
    const int h    = g4 & 1;              // 8-dim half this lane holds
    const bool lo  = (g4 >= 2);
    const int b    = blockIdx.x;
    const int gridN = gridDim.x;

    const int g = b >> 2;                 // row group (64 rows)
    const int s = b & 3;                  // train quarter
    const int r = w >> 2;                 // row tile within group
    const int q = w & 3;                  // train sub-slice

    const int nPad = TQ * 256;            // 16 sq-slices x TQ tiles x 16 pts

    __shared__ float red[16][16];

    // ---------------- Phase A: pack this block's share ----------------
    const int ppb = (nPad + gridN - 1) / gridN;
    for (int i = tid; i < ppb * 2; i += 1024) {
        int pt = b * ppb + (i >> 1);
        int hf = i & 1;
        if (pt < nPad) {
            const float4* p =
                (const float4*)(trainX + (size_t)min(pt, nTrain - 1) * 16) + hf * 2;
            float4 qa = p[0], qb = p[1];
            float pn = ((qa.x*qa.x + qa.y*qa.y) + (qa.z*qa.z + qa.w*qa.w))
                     + ((qb.x*qb.x + qb.y*qb.y) + (qb.z*qb.z + qb.w*qb.w));
            float n  = (pt < nTrain) ? (-0.5f * LOG2E) * pn : -1e30f;
            unsigned int u0 = cvtpk_bf16(qa.x, qa.y);
            unsigned int u1 = cvtpk_bf16(qa.z, qa.w);
            unsigned int u2 = cvtpk_bf16(qb.x, qb.y);
            unsigned int u3 = cvtpk_bf16(qb.z, qb.w);
            unsigned int u3n = cvtpk_bf16(qb.z, n);
            pk[(size_t)pt * 4 + hf]     = make_uint4(u0, u1, u2, u3);
            pk[(size_t)pt * 4 + hf + 2] = make_uint4(u0, u1, u2, u3n);
        }
    }

    // ---- A fragment prep (independent of pack; hides pack latency) ----
    const int rbase = g * 64 + r * 16;
    const int m = min(rbase + l4, nTest - 1);
    const float4* xp = (const float4*)(testX + (size_t)m * 16);
    float4 x0 = xp[0], x1 = xp[1], x2 = xp[2], x3 = xp[3];
    x0.x *= LOG2E; x0.y *= LOG2E; x0.z *= LOG2E; x0.w *= LOG2E;
    x1.x *= LOG2E; x1.y *= LOG2E; x1.z *= LOG2E; x1.w *= LOG2E;
    x2.x *= LOG2E; x2.y *= LOG2E; x2.z *= LOG2E; x2.w *= LOG2E;
    x3.x *= LOG2E; x3.y *= LOG2E; x3.z *= LOG2E; x3.w *= LOG2E;
    float xn = ((x0.x*x0.x + x0.y*x0.y) + (x0.z*x0.z + x0.w*x0.w))
             + ((x1.x*x1.x + x1.y*x1.y) + (x1.z*x1.z + x1.w*x1.w))
             + ((x2.x*x2.x + x2.y*x2.y) + (x2.z*x2.z + x2.w*x2.w))
             + ((x3.x*x3.x + x3.y*x3.y) + (x3.z*x3.z + x3.w*x3.w));
    xn *= 0.5f / LOG2E;                   // 0.5*log2e*||x||^2 of row rbase+l4

    float fx[8];
    fx[0] = h ? x2.x : x0.x;  fx[1] = h ? x2.y : x0.y;
    fx[2] = h ? x2.z : x0.z;  fx[3] = h ? x2.w : x0.w;
    fx[4] = h ? x3.x : x1.x;  fx[5] = h ? x3.y : x1.y;
    fx[6] = h ? x3.z : x1.z;  fx[7] = h ? x3.w : x1.w;

    short8 afrag;
    #pragma unroll
    for (int i = 0; i < 8; ++i) {
        float v = fx[i];
        unsigned short hb = f2bf(v);
        float hfv = __uint_as_float((unsigned int)hb << 16);
        unsigned short lb = f2bf(v - hfv);
        afrag[i] = (short)(lo ? lb : hb);  // k<16: hi, k>=16: lo
    }
    if (lo) afrag[7] = (short)0x3F80;      // bf16(1.0) at k=23 / k=31

    f32x4 nxv;                             // invariant MFMA C operand
    #pragma unroll
    for (int j = 0; j < 4; ++j)
        nxv[j] = -__shfl(xn, (lane & 48) + g4 * 4 + j);

    __threadfence();
    gridg.sync();

    // ---------------- Phase B: MFMA over packed image ----------------
    const short8* pkb = (const short8*)pk
                      + ((size_t)(s * 4 + q) * TQ * 16) * 4 + l4 * 4 + g4;

    float rsA[4] = {0,0,0,0}, rsB[4] = {0,0,0,0};
    for (int t = 0; t < TQ; t += 4) {
        short8 b0 = pkb[(size_t)(t+0) * 64];
        short8 b1 = pkb[(size_t)(t+1) * 64];
        short8 b2 = pkb[(size_t)(t+2) * 64];
        short8 b3 = pkb[(size_t)(t+3) * 64];
        f32x4 c0 = __builtin_amdgcn_mfma_f32_16x16x32_bf16(afrag, b0, nxv, 0,0,0);
        f32x4 c1 = __builtin_amdgcn_mfma_f32_16x16x32_bf16(afrag, b1, nxv, 0,0,0);
        f32x4 c2 = __builtin_amdgcn_mfma_f32_16x16x32_bf16(afrag, b2, nxv, 0,0,0);
        f32x4 c3 = __builtin_amdgcn_mfma_f32_16x16x32_bf16(afrag, b3, nxv, 0,0,0);
        #pragma unroll
        for (int j = 0; j < 4; ++j) {
            rsA[j] += __builtin_amdgcn_exp2f(c0[j]);
            rsB[j] += __builtin_amdgcn_exp2f(c1[j]);
            rsA[j] += __builtin_amdgcn_exp2f(c2[j]);
            rsB[j] += __builtin_amdgcn_exp2f(c3[j]);
        }
    }

    // Reduce across the 16 columns (low-4 lane bits).
    float rs0 = rsA[0] + rsB[0], rs1 = rsA[1] + rsB[1];
    float rs2 = rsA[2] + rsB[2], rs3 = rsA[3] + rsB[3];
    #pragma unroll
    for (int off = 1; off <= 8; off <<= 1) {
        rs0 += __shfl_xor(rs0, off);
        rs1 += __shfl_xor(rs1, off);
        rs2 += __shfl_xor(rs2, off);
        rs3 += __shfl_xor(rs3, off);
    }
    if (l4 == 0) {
        red[w][g4 * 4 + 0] = rs0;
        red[w][g4 * 4 + 1] = rs1;
        red[w][g4 * 4 + 2] = rs2;
        red[w][g4 * 4 + 3] = rs3;
    }
    __syncthreads();

    // Combine the 4 q-slices per row-tile; store partials[s][row].
    if (tid < 64) {
        int rt = tid >> 4, i = tid & 15;
        float v = red[rt*4+0][i] + red[rt*4+1][i]
                + red[rt*4+2][i] + red[rt*4+3][i];
        partials[(size_t)s * (G * 64) + g * 64 + tid] = v;
    }

    __threadfence();
    gridg.sync();

    // ---------------- Phase C: finalize ----------------
    if (b < G && tid < 64) {
        int row = b * 64 + tid;
        if (row < nTest) {
            const size_t P = (size_t)G * 64;
            float ssum = partials[0*P + row] + partials[1*P + row]
                       + partials[2*P + row] + partials[3*P + row];
            out[row] = __logf(ssum) - Z;
        }
    }
}

extern "C" void kernel_launch(void* const* d_in, const int* in_sizes, int n_in,
                              void* d_out, int out_size, void* d_ws, size_t ws_size,
                              hipStream_t stream) {
    const float* testX  = (const float*)d_in[0];
    const float* trainX = (const float*)d_in[1];
    float* out = (float*)d_out;

    const int D = 16;
    int nTest  = in_sizes[0] / D;   // 4096
    int nTrain = in_sizes[1] / D;   // 8192

    const float Z = 0.5f * (float)D * logf(2.0f * (float)M_PI) + logf((float)nTrain);

    // 16 (s,q) slices; TQ = 16-pt tiles per slice, multiple of 4.
    int tiles = (nTrain + 15) / 16;
    int TQ = (tiles + 15) / 16;
    TQ = (TQ + 3) & ~3;                   // 32 at bench size
    int nPad = TQ * 256;                  // 8192

    int G = (nTest + 63) / 64;            // 64 row groups
    int gridN = G * 4;                    // 256 blocks

    // ws: packed image (nPad*64B) | partials (4 * G*64 * 4B)
    uint4* pk       = (uint4*)d_ws;
    float* partials = (float*)((char*)d_ws + (size_t)nPad * 64);

    void* args[] = { (void*)&testX, (void*)&trainX, (void*)&pk,
                     (void*)&partials, (void*)&out,
                     (void*)&nTest, (void*)&nTrain, (void*)&TQ,
                     (void*)&G, (void*)&Z };
    hipLaunchCooperativeKernel((const void*)kde_coop, dim3(gridN), dim3(1024),
                               args, 0, stream);
}

// Round 15
// 16.154 us; speedup vs baseline: 12.4860x; 12.4860x over previous
//
#include <hip/hip_runtime.h>
#include <math.h>

#define LOG2E 1.4426950408889634f
#define LN2   0.6931471805599453f
#define NW 16   // waves per block
#define CH 64   // train points staged per chunk per wave (= 2 tiles of 32)

typedef short short8 __attribute__((ext_vector_type(8)));
typedef float f32x16 __attribute__((ext_vector_type(16)));

__device__ inline unsigned int cvtpk_bf16(float lo, float hi) {
    unsigned int r;
    asm("v_cvt_pk_bf16_f32 %0, %1, %2" : "=v"(r) : "v"(lo), "v"(hi));
    return r;   // low16 = bf16(lo), high16 = bf16(hi)
}

// ONE dispatch. grid = nTest/32 blocks x 1024 threads (16 waves, 1 blk/CU).
// Block owns 32 test rows (mfma_f32_32x32x16_bf16: M=32, N=32 train pts,
// K=16 = feature dim exactly -> no lo-compensation). Waves partition train
// (512 pts = 8 chunks of 64 = 2 tiles each), staging into PRIVATE 2KB LDS:
// 32B/pt (2 bf16 variants: dims0-7, dims8-15) XOR-swizzled for uniform
// banks, + f32 weight w = exp2(-0.5*log2e*||y||^2) (padded pts: w=0).
// Inner per 32-pt tile: 1 ds_read_b128 (1KB fully unique) + 1 ds_read_b32
// (w, broadcast-pair) + 1 MFMA (C=0) + 16 exp2 + 16 fma.
// exponent identity: sum exp2(dot-xn-yn) = exp2(-xn) * sum exp2(dot)*w;
// -xn*ln2 folds into the final log. No barriers in the loop (wave-private
// LDS, in-order per-wave DS ops — R11-proven).
__global__ __launch_bounds__(1024, 4) void kde_fused(
    const float* __restrict__ testX, const float* __restrict__ trainX,
    float* __restrict__ out, int nTest, int nTrain, int nch, float Z)
{
    const int tid  = threadIdx.x;
    const int lane = tid & 63;
    const int w    = tid >> 6;            // wave 0..15
    const int c    = lane & 31;           // MFMA row/col index
    const int half = lane >> 5;           // k-half (dims 0-7 / 8-15)
    const int rowBase = blockIdx.x * 32;

    __shared__ short8 stage[NW][2 * CH];            // 32 KB (2 tiles x 64 units)
    __shared__ float  wbuf[NW][CH];                 // 4 KB
    __shared__ float  xnbuf[32];
    __shared__ __align__(16) float red2[NW][32][36];// 73.7 KB (36: 16B-align + bank spread)
    __shared__ float  red3[32][33];                 // 4.2 KB

    // ---- A fragment: rows rowBase..+31, dims half*8..+7, bf16(x*log2e) ----
    const int mrow = min(rowBase + c, nTest - 1);
    const float4* xp = (const float4*)(testX + (size_t)mrow * 16) + half * 2;
    float4 xa = xp[0], xb = xp[1];
    float f0 = xa.x*LOG2E, f1 = xa.y*LOG2E, f2 = xa.z*LOG2E, f3 = xa.w*LOG2E;
    float f4 = xb.x*LOG2E, f5 = xb.y*LOG2E, f6 = xb.z*LOG2E, f7 = xb.w*LOG2E;
    float pn = ((f0*f0 + f1*f1) + (f2*f2 + f3*f3))
             + ((f4*f4 + f5*f5) + (f6*f6 + f7*f7));
    float xn2 = (pn + __shfl_xor(pn, 32)) * (0.5f / LOG2E);  // 0.5*log2e*||x||^2
    union { unsigned int u[4]; short8 s; } au;
    au.u[0] = cvtpk_bf16(f0, f1);
    au.u[1] = cvtpk_bf16(f2, f3);
    au.u[2] = cvtpk_bf16(f4, f5);
    au.u[3] = cvtpk_bf16(f6, f7);
    const short8 afrag = au.s;
    if (w == 0 && half == 0) xnbuf[c] = xn2;

    // ---- wave's train slice ----
    const int nMax = nTrain - 1;
    const int tb   = w * nch * CH;
    // read unit within a tile (XOR swizzle, bijective, uniform banks)
    const int rdU  = (c * 2 + half) ^ ((c >> 2) & 7);

    float4 q0, q1, q2, q3; float wv;
    auto LOADRAW = [&](int ch) {          // lane loads pt ch*64+lane (full 64B)
        int gi = tb + ch * CH + lane;
        const float4* p = (const float4*)(trainX + (size_t)min(gi, nMax) * 16);
        q0 = p[0]; q1 = p[1]; q2 = p[2]; q3 = p[3];
        float nrm = ((q0.x*q0.x + q0.y*q0.y) + (q0.z*q0.z + q0.w*q0.w))
                  + ((q1.x*q1.x + q1.y*q1.y) + (q1.z*q1.z + q1.w*q1.w))
                  + ((q2.x*q2.x + q2.y*q2.y) + (q2.z*q2.z + q2.w*q2.w))
                  + ((q3.x*q3.x + q3.y*q3.y) + (q3.z*q3.z + q3.w*q3.w));
        wv = (gi <= nMax) ? __builtin_amdgcn_exp2f(-0.5f * LOG2E * nrm) : 0.0f;
    };
    auto WRITEPT = [&]() {
        const int pp = lane & 31, ti = lane >> 5;
        const int u0 = (pp * 2 + 0) ^ ((pp >> 2) & 7);
        const int u1 = (pp * 2 + 1) ^ ((pp >> 2) & 7);
        union { unsigned int u[4]; short8 s; } b0, b1;
        b0.u[0] = cvtpk_bf16(q0.x, q0.y); b0.u[1] = cvtpk_bf16(q0.z, q0.w);
        b0.u[2] = cvtpk_bf16(q1.x, q1.y); b0.u[3] = cvtpk_bf16(q1.z, q1.w);
        b1.u[0] = cvtpk_bf16(q2.x, q2.y); b1.u[1] = cvtpk_bf16(q2.z, q2.w);
        b1.u[2] = cvtpk_bf16(q3.x, q3.y); b1.u[3] = cvtpk_bf16(q3.z, q3.w);
        stage[w][ti * 64 + u0] = b0.s;    // variant 0: dims 0-7
        stage[w][ti * 64 + u1] = b1.s;    // variant 1: dims 8-15
        wbuf[w][lane] = wv;
    };

    float rs[16];
    #pragma unroll
    for (int i = 0; i < 16; ++i) rs[i] = 0.0f;

    auto INNER = [&]() {
        #pragma unroll
        for (int t = 0; t < 2; ++t) {
            short8 bf = stage[w][t * 64 + rdU];
            float  wt = wbuf[w][t * 32 + c];
            f32x16 z = {0.f,0.f,0.f,0.f,0.f,0.f,0.f,0.f,
                        0.f,0.f,0.f,0.f,0.f,0.f,0.f,0.f};
            f32x16 d = __builtin_amdgcn_mfma_f32_32x32x16_bf16(afrag, bf, z, 0,0,0);
            #pragma unroll
            for (int r = 0; r < 16; ++r)
                rs[r] += __builtin_amdgcn_exp2f(d[r]) * wt;
        }
    };

    // Pipeline: load(ch+1) || inner(ch) || write(ch+1); wave-private LDS.
    LOADRAW(0);
    WRITEPT();
    for (int ch = 0; ch < nch - 1; ++ch) {
        LOADRAW(ch + 1);
        INNER();
        WRITEPT();
    }
    INNER();

    // ---- reduce over train cols: rs[reg] holds col c, rows r(reg,half) ----
    // row = (reg&3) + 8*(reg>>2) + 4*half; regs 4q..4q+3 are contiguous rows.
    #pragma unroll
    for (int qd = 0; qd < 4; ++qd) {
        float4 v = make_float4(rs[qd*4+0], rs[qd*4+1], rs[qd*4+2], rs[qd*4+3]);
        *(float4*)&red2[w][c][half * 4 + qd * 8] = v;
    }
    __syncthreads();

    // pass 1: 1024 threads: row = t&31, seg = t>>5 (16 waves x 2 col-halves)
    {
        int row = tid & 31, seg = tid >> 5;
        int wv2 = seg >> 1, cb = (seg & 1) * 16;
        float s = 0.0f;
        #pragma unroll
        for (int i = 0; i < 16; ++i) s += red2[wv2][cb + i][row];
        red3[row][seg] = s;
    }
    __syncthreads();

    // pass 2: 32 threads finalize rows
    if (tid < 32) {
        int row = rowBase + tid;
        if (row < nTest) {
            float s = 0.0f;
            #pragma unroll
            for (int k = 0; k < 32; ++k) s += red3[tid][k];
            out[row] = __logf(s) - xnbuf[tid] * LN2 - Z;
        }
    }
}

extern "C" void kernel_launch(void* const* d_in, const int* in_sizes, int n_in,
                              void* d_out, int out_size, void* d_ws, size_t ws_size,
                              hipStream_t stream) {
    const float* testX  = (const float*)d_in[0];
    const float* trainX = (const float*)d_in[1];
    float* out = (float*)d_out;

    const int D = 16;
    const int nTest  = in_sizes[0] / D;   // 4096
    const int nTrain = in_sizes[1] / D;   // 8192

    const float Z = 0.5f * (float)D * logf(2.0f * (float)M_PI) + logf((float)nTrain);

    const int nch  = (nTrain + NW * CH - 1) / (NW * CH);  // chunks per wave (8)
    const int grid = (nTest + 31) / 32;                   // 128 blocks, 32 rows each

    kde_fused<<<grid, 1024, 0, stream>>>(testX, trainX, out, nTest, nTrain, nch, Z);
}

// Round 16
// 15.057 us; speedup vs baseline: 13.3962x; 1.0729x over previous
//
#include <hip/hip_runtime.h>
#include <math.h>

#define LOG2E 1.4426950408889634f
#define LN2   0.6931471805599453f
#define NW 16   // waves per block
#define CH 64   // train points staged per chunk per wave (= 2 tiles of 32)

typedef short short8 __attribute__((ext_vector_type(8)));
typedef float f32x16 __attribute__((ext_vector_type(16)));

__device__ inline unsigned int cvtpk_bf16(float lo, float hi) {
    unsigned int r;
    asm("v_cvt_pk_bf16_f32 %0, %1, %2" : "=v"(r) : "v"(lo), "v"(hi));
    return r;   // low16 = bf16(lo), high16 = bf16(hi)
}

// ONE dispatch. grid = nTest/16 blocks (256 -> ALL CUs busy) x 1024 threads
// (16 waves). Block owns 16 test rows; A-operand M=32 is half-padded (rows
// 16-31 duplicate rows 0-15); only output regs 0-7 (rows 0-15) are consumed,
// so the M-waste hits only the non-bottleneck MFMA pipe.
// Waves partition train (512 pts = 8 chunks of 64 = 2 tiles of 32), staging
// into PRIVATE 2KB LDS: 32B/pt bf16 (2 variants: dims0-7, dims8-15),
// XOR-swizzled, + f32 weight w = exp2(-0.5*log2e*||y||^2) (padded pts w=0).
// Inner per chunk: 2x{ds_read_b128 + ds_read_b32} -> 2 MFMAs issued
// back-to-back -> consume tile0's 8 exp2+fma (hides tile1's MFMA) -> tile1.
// Identity: sum exp2(dot - xn - yn) = exp2(-xn) * sum exp2(dot) * w;
// -xn*ln2 folds into the final log. No barriers in the staging/inner loop.
__global__ __launch_bounds__(1024, 4) void kde_fused(
    const float* __restrict__ testX, const float* __restrict__ trainX,
    float* __restrict__ out, int nTest, int nTrain, int nch, float Z)
{
    const int tid  = threadIdx.x;
    const int lane = tid & 63;
    const int w    = tid >> 6;            // wave 0..15
    const int c    = lane & 31;           // MFMA col (train pt) / A-row index
    const int half = lane >> 5;           // k-half (dims 0-7 / 8-15)
    const int rowBase = blockIdx.x * 16;

    __shared__ short8 stage[NW][2 * CH];            // 32 KB
    __shared__ float  wbuf[NW][CH];                 // 4 KB
    __shared__ float  xnbuf[16];
    __shared__ __align__(16) float red2[NW][32][20];// 40 KB
    __shared__ float  red3[16][68];                 // 4.3 KB

    // ---- A fragment: rows rowBase+(c&15) (dup'd for c>=16), bf16(x*log2e) ----
    const int mrow = min(rowBase + (c & 15), nTest - 1);
    const float4* xp = (const float4*)(testX + (size_t)mrow * 16) + half * 2;
    float4 xa = xp[0], xb = xp[1];
    float f0 = xa.x*LOG2E, f1 = xa.y*LOG2E, f2 = xa.z*LOG2E, f3 = xa.w*LOG2E;
    float f4 = xb.x*LOG2E, f5 = xb.y*LOG2E, f6 = xb.z*LOG2E, f7 = xb.w*LOG2E;
    float pn = ((f0*f0 + f1*f1) + (f2*f2 + f3*f3))
             + ((f4*f4 + f5*f5) + (f6*f6 + f7*f7));
    float xn2 = (pn + __shfl_xor(pn, 32)) * (0.5f / LOG2E);  // 0.5*log2e*||x||^2
    union { unsigned int u[4]; short8 s; } au;
    au.u[0] = cvtpk_bf16(f0, f1);
    au.u[1] = cvtpk_bf16(f2, f3);
    au.u[2] = cvtpk_bf16(f4, f5);
    au.u[3] = cvtpk_bf16(f6, f7);
    const short8 afrag = au.s;
    if (w == 0 && half == 0 && c < 16) xnbuf[c] = xn2;

    // ---- wave's train slice ----
    const int nMax = nTrain - 1;
    const int tb   = w * nch * CH;
    const int rdU  = (c * 2 + half) ^ ((c >> 2) & 7);   // swizzled read unit

    float4 q0, q1, q2, q3; float wv;
    auto LOADRAW = [&](int ch) {          // lane loads pt ch*64+lane (64B)
        int gi = tb + ch * CH + lane;
        const float4* p = (const float4*)(trainX + (size_t)min(gi, nMax) * 16);
        q0 = p[0]; q1 = p[1]; q2 = p[2]; q3 = p[3];
        float nrm = ((q0.x*q0.x + q0.y*q0.y) + (q0.z*q0.z + q0.w*q0.w))
                  + ((q1.x*q1.x + q1.y*q1.y) + (q1.z*q1.z + q1.w*q1.w))
                  + ((q2.x*q2.x + q2.y*q2.y) + (q2.z*q2.z + q2.w*q2.w))
                  + ((q3.x*q3.x + q3.y*q3.y) + (q3.z*q3.z + q3.w*q3.w));
        wv = (gi <= nMax) ? __builtin_amdgcn_exp2f(-0.5f * LOG2E * nrm) : 0.0f;
    };
    auto WRITEPT = [&]() {
        const int pp = lane & 31, ti = lane >> 5;
        const int u0 = (pp * 2 + 0) ^ ((pp >> 2) & 7);
        const int u1 = (pp * 2 + 1) ^ ((pp >> 2) & 7);
        union { unsigned int u[4]; short8 s; } b0, b1;
        b0.u[0] = cvtpk_bf16(q0.x, q0.y); b0.u[1] = cvtpk_bf16(q0.z, q0.w);
        b0.u[2] = cvtpk_bf16(q1.x, q1.y); b0.u[3] = cvtpk_bf16(q1.z, q1.w);
        b1.u[0] = cvtpk_bf16(q2.x, q2.y); b1.u[1] = cvtpk_bf16(q2.z, q2.w);
        b1.u[2] = cvtpk_bf16(q3.x, q3.y); b1.u[3] = cvtpk_bf16(q3.z, q3.w);
        stage[w][ti * 64 + u0] = b0.s;    // variant 0: dims 0-7
        stage[w][ti * 64 + u1] = b1.s;    // variant 1: dims 8-15
        wbuf[w][lane] = wv;
    };

    float rs[8];
    #pragma unroll
    for (int i = 0; i < 8; ++i) rs[i] = 0.0f;

    const f32x16 zc = {0.f,0.f,0.f,0.f,0.f,0.f,0.f,0.f,
                       0.f,0.f,0.f,0.f,0.f,0.f,0.f,0.f};
    auto INNER = [&]() {
        // issue both tiles' reads + both MFMAs, then consume (MFMA1 hides
        // under tile0's exp2/fma chain).
        short8 bf0 = stage[w][rdU];
        short8 bf1 = stage[w][64 + rdU];
        float  wt0 = wbuf[w][c];
        float  wt1 = wbuf[w][32 + c];
        f32x16 d0 = __builtin_amdgcn_mfma_f32_32x32x16_bf16(afrag, bf0, zc, 0,0,0);
        f32x16 d1 = __builtin_amdgcn_mfma_f32_32x32x16_bf16(afrag, bf1, zc, 0,0,0);
        #pragma unroll
        for (int r = 0; r < 8; ++r)
            rs[r] += __builtin_amdgcn_exp2f(d0[r]) * wt0;
        #pragma unroll
        for (int r = 0; r < 8; ++r)
            rs[r] += __builtin_amdgcn_exp2f(d1[r]) * wt1;
    };

    // Pipeline: load(ch+1) || inner(ch) || write(ch+1); wave-private LDS.
    LOADRAW(0);
    WRITEPT();
    for (int ch = 0; ch < nch - 1; ++ch) {
        LOADRAW(ch + 1);
        INNER();
        WRITEPT();
    }
    INNER();

    // ---- reduce: rs[reg] = col c, row (reg&3)+8*(reg>>2)+4*half (0-15) ----
    {
        float4 v0 = make_float4(rs[0], rs[1], rs[2], rs[3]);
        float4 v1 = make_float4(rs[4], rs[5], rs[6], rs[7]);
        *(float4*)&red2[w][c][half * 4]     = v0;   // rows 0-3 + 4*half
        *(float4*)&red2[w][c][8 + half * 4] = v1;   // rows 8-11 + 4*half
    }
    __syncthreads();

    // pass 1: 1024 threads: row = t&15, seg = t>>4 (16 waves x 4 col-groups)
    {
        int row = tid & 15, seg = tid >> 4;
        int wv2 = seg >> 2, cb = (seg & 3) * 8;
        float s = 0.0f;
        #pragma unroll
        for (int i = 0; i < 8; ++i) s += red2[wv2][cb + i][row];
        red3[row][seg] = s;
    }
    __syncthreads();

    // pass 2: 16 threads finalize rows
    if (tid < 16) {
        int row = rowBase + tid;
        if (row < nTest) {
            float s = 0.0f;
            #pragma unroll
            for (int k = 0; k < 64; ++k) s += red3[tid][k];
            out[row] = __logf(s) - xnbuf[tid] * LN2 - Z;
        }
    }
}

extern "C" void kernel_launch(void* const* d_in, const int* in_sizes, int n_in,
                              void* d_out, int out_size, void* d_ws, size_t ws_size,
                              hipStream_t stream) {
    const float* testX  = (const float*)d_in[0];
    const float* trainX = (const float*)d_in[1];
    float* out = (float*)d_out;

    const int D = 16;
    const int nTest  = in_sizes[0] / D;   // 4096
    const int nTrain = in_sizes[1] / D;   // 8192

    const float Z = 0.5f * (float)D * logf(2.0f * (float)M_PI) + logf((float)nTrain);

    const int nch  = (nTrain + NW * CH - 1) / (NW * CH);  // chunks per wave (8)
    const int grid = (nTest + 15) / 16;                   // 256 blocks, 16 rows

    kde_fused<<<grid, 1024, 0, stream>>>(testX, trainX, out, nTest, nTrain, nch, Z);
}